// Round 13
// baseline (64.627 us; speedup 1.0000x reference)
//
#include <hip/hip_runtime.h>
#include <math.h>

#define D_MODEL 2048
#define NE      64
#define TB      64               // tokens per fused block
#define KC      128              // fp32 k per chunk
#define NCH     (D_MODEL / KC)   // 16 chunks (KS=1: no split, no partials)
#define FB_KC   32
#define FB_NCH  (D_MODEL / FB_KC)

typedef _Float16 half8 __attribute__((ext_vector_type(8)));
typedef float    f32x4 __attribute__((ext_vector_type(4)));

// two-term split of one float into fp16 high+low at ext-vector slot J.
// Named vars + constant indices only (rule #20 — unions/arrays → scratch).
#define CVT1(F, HV, LV, J) do {                                               \
    float _f = (F);                                                           \
    _Float16 _h = (_Float16)_f;                                               \
    HV[J] = _h;                                                               \
    LV[J] = (_Float16)(_f - (float)_h);                                       \
} while (0)

// ---------------- W -> (Wh, Wl) fp16 split, scaled x64 (r12-proven) ---------
__global__ __launch_bounds__(256) void wcvt_kernel(
    const float* __restrict__ W, short* __restrict__ Wh, short* __restrict__ Wl)
{
    const int e = blockIdx.x, t = threadIdx.x, c = t * 8;
    const float* src = W + (size_t)e * D_MODEL + c;
    float4 v0 = *(const float4*)src;
    float4 v1 = *(const float4*)(src + 4);
    half8 hv, lv;
    CVT1(v0.x * 64.0f, hv, lv, 0); CVT1(v0.y * 64.0f, hv, lv, 1);
    CVT1(v0.z * 64.0f, hv, lv, 2); CVT1(v0.w * 64.0f, hv, lv, 3);
    CVT1(v1.x * 64.0f, hv, lv, 4); CVT1(v1.y * 64.0f, hv, lv, 5);
    CVT1(v1.z * 64.0f, hv, lv, 6); CVT1(v1.w * 64.0f, hv, lv, 7);
    *(half8*)(Wh + (size_t)e * D_MODEL + c) = hv;
    *(half8*)(Wl + (size_t)e * D_MODEL + c) = lv;
}

// ---------------- fused MFMA gemm (KS=1) + in-block stats -------------------
// logits*512 = (8x)(64w): 4 mfma/k-step (r11/r12-proven layout & swizzle).
// Depth-2 A prefetch (two named reg sets, parity-unrolled) covers ~900cyc
// HBM latency; W (L2-hot) depth-1, issued BEFORE A so counted vmcnt waits
// leave the younger A-loads in flight. Stats run in-block on sL aliased
// over the staging LDS -> zero partials traffic.
__global__ __launch_bounds__(256, 2) void router_fused(
    const float* __restrict__ x, const short* __restrict__ Whg,
    const short* __restrict__ Wlg, float* __restrict__ out,
    float* __restrict__ ws_prob, float* __restrict__ ws_z,
    int* __restrict__ ws_cnt, int Ntok)
{
    __shared__ __align__(16) char smem[65536];
    _Float16* Ah = (_Float16*)smem;           // [64][128] f16, swizzled
    _Float16* Al = (_Float16*)(smem + 16384);
    _Float16* Wh = (_Float16*)(smem + 32768);
    _Float16* Wl = (_Float16*)(smem + 49152);
    // stats region: aliased over Ah/Al/Wh after __syncthreads()
    float (*sL)[NE + 1] = (float (*)[NE + 1])smem;             // 16640 B
    float (*red4)[4]    = (float (*)[4])(smem + 20480);        // 1 KB
    int   (*arg4)[4]    = (int (*)[4])(smem + 24576);          // 1 KB
    float* smax         = (float*)(smem + 28672);
    float* sinv         = (float*)(smem + 28928);
    float (*spart)[NE]  = (float (*)[NE])(smem + 29184);       // 1 KB
    int*   hist         = (int*)(smem + 30720);

    const int t  = threadIdx.x;
    const int b  = blockIdx.x;
    const int m0 = b * TB;
    const int l  = t & 63;
    const int wv = t >> 6;                    // 0..3

    // staging map (r12-proven): item i: row = i*16+srow, 16B slot = sslt,
    // swizzled dest slot = sslt ^ (srow&7)
    const int srow  = t >> 4;                 // 0..15
    const int sslt  = t & 15;
    const int soff0 = ((sslt ^ (srow & 7)) << 3);

    float4 paA0, paA1, paA2, paA3, paA4, paA5, paA6, paA7;   // A set even
    float4 paB0, paB1, paB2, paB3, paB4, paB5, paB6, paB7;   // A set odd
    uint4  pwh0, pwh1, pwh2, pwh3, pwl0, pwl1, pwl2, pwl3;   // W current

#define PRE_A(P0, P1, P2, P3, P4, P5, P6, P7, KB) do {                        \
    const float* _a0 = x + (size_t)(m0 +  0 + srow) * D_MODEL + (KB) + sslt * 8; \
    const float* _a1 = x + (size_t)(m0 + 16 + srow) * D_MODEL + (KB) + sslt * 8; \
    const float* _a2 = x + (size_t)(m0 + 32 + srow) * D_MODEL + (KB) + sslt * 8; \
    const float* _a3 = x + (size_t)(m0 + 48 + srow) * D_MODEL + (KB) + sslt * 8; \
    P0 = *(const float4*)_a0; P1 = *(const float4*)(_a0 + 4);                 \
    P2 = *(const float4*)_a1; P3 = *(const float4*)(_a1 + 4);                 \
    P4 = *(const float4*)_a2; P5 = *(const float4*)(_a2 + 4);                 \
    P6 = *(const float4*)_a3; P7 = *(const float4*)(_a3 + 4);                 \
} while (0)

#define PRE_W(KB) do {                                                        \
    const size_t _w0 = (size_t)( 0 + srow) * D_MODEL + (KB) + sslt * 8;       \
    const size_t _w1 = (size_t)(16 + srow) * D_MODEL + (KB) + sslt * 8;       \
    const size_t _w2 = (size_t)(32 + srow) * D_MODEL + (KB) + sslt * 8;       \
    const size_t _w3 = (size_t)(48 + srow) * D_MODEL + (KB) + sslt * 8;       \
    pwh0 = *(const uint4*)&Whg[_w0]; pwh1 = *(const uint4*)&Whg[_w1];         \
    pwh2 = *(const uint4*)&Whg[_w2]; pwh3 = *(const uint4*)&Whg[_w3];         \
    pwl0 = *(const uint4*)&Wlg[_w0]; pwl1 = *(const uint4*)&Wlg[_w1];         \
    pwl2 = *(const uint4*)&Wlg[_w2]; pwl3 = *(const uint4*)&Wlg[_w3];         \
} while (0)

#define STORE_ITEM(I, PA, PB, PWH, PWL) do {                                  \
    half8 _hv, _lv;                                                           \
    CVT1((PA).x * 8.0f, _hv, _lv, 0); CVT1((PA).y * 8.0f, _hv, _lv, 1);       \
    CVT1((PA).z * 8.0f, _hv, _lv, 2); CVT1((PA).w * 8.0f, _hv, _lv, 3);       \
    CVT1((PB).x * 8.0f, _hv, _lv, 4); CVT1((PB).y * 8.0f, _hv, _lv, 5);       \
    CVT1((PB).z * 8.0f, _hv, _lv, 6); CVT1((PB).w * 8.0f, _hv, _lv, 7);       \
    const int _off = ((I) * 16 + srow) * 128 + soff0;                         \
    *(half8*)&Ah[_off] = _hv;                                                 \
    *(half8*)&Al[_off] = _lv;                                                 \
    *(uint4*)&Wh[_off] = PWH;                                                 \
    *(uint4*)&Wl[_off] = PWL;                                                 \
} while (0)

#define STORE_SET(P0, P1, P2, P3, P4, P5, P6, P7) do {                        \
    STORE_ITEM(0, P0, P1, pwh0, pwl0);                                        \
    STORE_ITEM(1, P2, P3, pwh1, pwl1);                                        \
    STORE_ITEM(2, P4, P5, pwh2, pwl2);                                        \
    STORE_ITEM(3, P6, P7, pwh3, pwl3);                                        \
} while (0)

#define MFMA_PHASE() do {                                                     \
    const int arow = wv * 16 + (l & 15);                                      \
    const int rsw  = l & 7;                                                   \
    _Pragma("unroll")                                                         \
    for (int kq = 0; kq < 4; ++kq) {                                          \
        const int s    = kq * 4 + (l >> 4);                                   \
        const int aoff = arow * 128 + ((s ^ rsw) << 3);                       \
        half8 ah = *(const half8*)&Ah[aoff];                                  \
        half8 al = *(const half8*)&Al[aoff];                                  \
        _Pragma("unroll")                                                     \
        for (int n = 0; n < 4; ++n) {                                         \
            const int woff = (n * 16 + (l & 15)) * 128 + ((s ^ rsw) << 3);    \
            half8 wh = *(const half8*)&Wh[woff];                              \
            half8 wl = *(const half8*)&Wl[woff];                              \
            f32x4 a = (n == 0) ? acc0 : (n == 1) ? acc1 : (n == 2) ? acc2 : acc3; \
            a = __builtin_amdgcn_mfma_f32_16x16x32_f16(al, wl, a, 0, 0, 0);   \
            a = __builtin_amdgcn_mfma_f32_16x16x32_f16(al, wh, a, 0, 0, 0);   \
            a = __builtin_amdgcn_mfma_f32_16x16x32_f16(ah, wl, a, 0, 0, 0);   \
            a = __builtin_amdgcn_mfma_f32_16x16x32_f16(ah, wh, a, 0, 0, 0);   \
            if (n == 0) acc0 = a; else if (n == 1) acc1 = a;                  \
            else if (n == 2) acc2 = a; else acc3 = a;                         \
        }                                                                     \
    }                                                                         \
} while (0)

    f32x4 acc0 = {0.f,0.f,0.f,0.f}, acc1 = {0.f,0.f,0.f,0.f};
    f32x4 acc2 = {0.f,0.f,0.f,0.f}, acc3 = {0.f,0.f,0.f,0.f};

    // prologue: A chunks 0,1 (depth 2) + W chunk 0
    PRE_A(paA0, paA1, paA2, paA3, paA4, paA5, paA6, paA7, 0);
    PRE_W(0);
    PRE_A(paB0, paB1, paB2, paB3, paB4, paB5, paB6, paB7, KC);

    for (int ch = 0; ch < NCH; ch += 2) {
        // ---- even chunk: consumes A set-A, W(ch) ----
        __builtin_amdgcn_s_barrier();
        STORE_SET(paA0, paA1, paA2, paA3, paA4, paA5, paA6, paA7);
        asm volatile("s_waitcnt lgkmcnt(0)" ::: "memory");
        __builtin_amdgcn_s_barrier();
        if (ch + 1 < NCH) PRE_W((ch + 1) * KC);          // W first (older)
        if (ch + 2 < NCH)                                 // A depth-2 refill
            PRE_A(paA0, paA1, paA2, paA3, paA4, paA5, paA6, paA7, (ch + 2) * KC);
        MFMA_PHASE();
        // ---- odd chunk: consumes A set-B, W(ch+1) ----
        __builtin_amdgcn_s_barrier();
        STORE_SET(paB0, paB1, paB2, paB3, paB4, paB5, paB6, paB7);
        asm volatile("s_waitcnt lgkmcnt(0)" ::: "memory");
        __builtin_amdgcn_s_barrier();
        if (ch + 2 < NCH) PRE_W((ch + 2) * KC);
        if (ch + 3 < NCH)
            PRE_A(paB0, paB1, paB2, paB3, paB4, paB5, paB6, paB7, (ch + 3) * KC);
        MFMA_PHASE();
    }

    // ---- stats in-block (r2-proven phases; sL aliases staging LDS) ----
    __syncthreads();                          // drain MFMA reads; smem reuse
    {
        const int rbase = wv * 16 + (l >> 4) * 4;        // m89 D-layout
        const int col0  = l & 15;
        #pragma unroll
        for (int q = 0; q < 4; ++q) {
            sL[rbase + q][ 0 + col0] = acc0[q] * (1.0f / 512.0f);
            sL[rbase + q][16 + col0] = acc1[q] * (1.0f / 512.0f);
            sL[rbase + q][32 + col0] = acc2[q] * (1.0f / 512.0f);
            sL[rbase + q][48 + col0] = acc3[q] * (1.0f / 512.0f);
        }
    }
    if (t < NE) hist[t] = 0;
    __syncthreads();

    {   // per-quarter argmax (4 threads per token, ascending -> first-max)
        const int m = t >> 2, qr = t & 3;
        float mx = -3.4e38f; int ag = 0;
        #pragma unroll
        for (int k = 0; k < 16; ++k) {
            const int e = qr * 16 + k;
            float v = sL[m][e];
            if (v > mx) { mx = v; ag = e; }
        }
        red4[m][qr] = mx; arg4[m][qr] = ag;
    }
    __syncthreads();
    if (t < 64) {                             // combine ascending: first-max
        const int m = t;
        float mx = red4[m][0]; int ag = arg4[m][0];
        #pragma unroll
        for (int qr = 1; qr < 4; ++qr)
            if (red4[m][qr] > mx) { mx = red4[m][qr]; ag = arg4[m][qr]; }
        smax[m] = mx;
        out[m0 + m] = (float)ag;              // expert_index
        atomicAdd(&hist[ag], 1);
    }
    __syncthreads();
    {   // per-quarter expsum
        const int m = t >> 2, qr = t & 3;
        const float mx = smax[m];
        float s = 0.f;
        #pragma unroll
        for (int k = 0; k < 16; ++k) s += expf(sL[m][qr * 16 + k] - mx);
        red4[m][qr] = s;
    }
    __syncthreads();
    if (t < 64) {
        const int m = t;
        float s = ((red4[m][0] + red4[m][1]) + red4[m][2]) + red4[m][3];
        float inv = 1.f / s;
        sinv[m] = inv;
        out[Ntok + m0 + m] = inv;             // expert_prob
        float lse = smax[m] + logf(s);
        float z = lse * lse;
        #pragma unroll
        for (int off = 32; off > 0; off >>= 1) z += __shfl_down(z, off, 64);
        if (t == 0) ws_z[b] = z;
    }
    __syncthreads();
    {   // probsum: wave mg covers 16 tokens, lane = expert
        const int e = t & 63, mg = t >> 6;
        float pa = 0.f;
        #pragma unroll
        for (int k = 0; k < 16; ++k) {
            const int m = mg * 16 + k;
            pa += expf(sL[m][e] - smax[m]) * sinv[m];
        }
        spart[mg][e] = pa;
    }
    __syncthreads();
    if (t < NE) {
        ws_prob[b * NE + t] = ((spart[0][t] + spart[1][t]) + spart[2][t]) + spart[3][t];
        ws_cnt[b * NE + t]  = hist[t];
    }
}

// ---------------- final reduce (r10/r12-proven) -----------------------------
__global__ __launch_bounds__(256) void router_final2(
    const float* __restrict__ ws_prob, const float* __restrict__ ws_z,
    const int* __restrict__ ws_cnt, float* __restrict__ out,
    int Ntok, int nblocks)
{
    __shared__ float sp[4][NE];
    __shared__ int   sc[4][NE];
    __shared__ float sz[4];

    const int e = threadIdx.x & 63, g = threadIdx.x >> 6;
    const int per = nblocks / 4;
    const int hi  = (g == 3) ? nblocks : (g + 1) * per;

    float ps = 0.f; int c = 0;
    for (int blk = g * per; blk < hi; ++blk) {       // fixed partition
        ps += ws_prob[blk * NE + e];
        c  += ws_cnt[blk * NE + e];
    }
    sp[g][e] = ps; sc[g][e] = c;

    float z = 0.f;
    for (int blk = (int)threadIdx.x; blk < nblocks; blk += 256) z += ws_z[blk];
    #pragma unroll
    for (int off = 32; off > 0; off >>= 1) z += __shfl_down(z, off, 64);
    if (e == 0) sz[g] = z;
    __syncthreads();

    if (threadIdx.x < 64) {
        const int ee = threadIdx.x;
        float pst = ((sp[0][ee] + sp[1][ee]) + sp[2][ee]) + sp[3][ee];
        int   ct  = ((sc[0][ee] + sc[1][ee]) + sc[2][ee]) + sc[3][ee];
        out[2 * Ntok + ee] = (float)ct;              // counts

        float fN = (float)Ntok;
        float fp = ((float)ct / fN) * (pst / fN);
        #pragma unroll
        for (int off = 32; off > 0; off >>= 1) fp += __shfl_down(fp, off, 64);
        if (ee == 0) {
            float zt = ((sz[0] + sz[1]) + sz[2]) + sz[3];
            int cap = (Ntok + NE - 1) / NE;
            if (cap < 4) cap = 4;
            float aux = 0.01f * (float)NE * fp + 1e-3f * (zt / fN);
            out[2 * Ntok + NE]     = (float)cap;     // capacity
            out[2 * Ntok + NE + 1] = aux;            // aux_loss
        }
    }
}

// ---------------- fallback (round-1 proven fused fp32 path) -----------------
__global__ __launch_bounds__(256) void router_main_fb(
    const float* __restrict__ x, const float* __restrict__ W,
    float* __restrict__ out, float* __restrict__ ws_prob,
    float* __restrict__ ws_z, int* __restrict__ ws_cnt, int Ntok)
{
    __shared__ __align__(16) float sX[FB_KC][68];
    __shared__ __align__(16) float sW[FB_KC][68];
    __shared__ float sL[64][65];
    __shared__ float smax[64], sinv[64];
    __shared__ float spart[4][NE];
    __shared__ int   hist[NE];

    const int t = threadIdx.x, b = blockIdx.x, m0 = b * 64;
    const int mq = t & 15, nq = t >> 4;
    const int r1 = t >> 3, r2 = r1 + 32, c1 = (t & 7) << 2;
    const float* xp1 = x + (size_t)(m0 + r1) * D_MODEL + c1;
    const float* xp2 = x + (size_t)(m0 + r2) * D_MODEL + c1;
    const float* wp1 = W + (size_t)r1 * D_MODEL + c1;
    const float* wp2 = W + (size_t)r2 * D_MODEL + c1;
    float4 ax1 = *(const float4*)xp1, ax2 = *(const float4*)xp2;
    float4 aw1 = *(const float4*)wp1, aw2 = *(const float4*)wp2;
    float a1[4][4] = {}, a2[4][4] = {};
    for (int ch = 0; ch < FB_NCH; ++ch) {
        __syncthreads();
        sX[c1+0][r1] = ax1.x; sX[c1+1][r1] = ax1.y; sX[c1+2][r1] = ax1.z; sX[c1+3][r1] = ax1.w;
        sX[c1+0][r2] = ax2.x; sX[c1+1][r2] = ax2.y; sX[c1+2][r2] = ax2.z; sX[c1+3][r2] = ax2.w;
        sW[c1+0][r1] = aw1.x; sW[c1+1][r1] = aw1.y; sW[c1+2][r1] = aw1.z; sW[c1+3][r1] = aw1.w;
        sW[c1+0][r2] = aw2.x; sW[c1+1][r2] = aw2.y; sW[c1+2][r2] = aw2.z; sW[c1+3][r2] = aw2.w;
        __syncthreads();
        if (ch + 1 < FB_NCH) {
            xp1 += FB_KC; xp2 += FB_KC; wp1 += FB_KC; wp2 += FB_KC;
            ax1 = *(const float4*)xp1; ax2 = *(const float4*)xp2;
            aw1 = *(const float4*)wp1; aw2 = *(const float4*)wp2;
        }
        #pragma unroll
        for (int k = 0; k < FB_KC; ++k) {
            float4 xa = *(const float4*)&sX[k][mq << 2];
            float4 wb = *(const float4*)&sW[k][nq << 2];
            float (*A)[4] = (k < FB_KC / 2) ? a1 : a2;
            A[0][0] = fmaf(xa.x, wb.x, A[0][0]); A[0][1] = fmaf(xa.x, wb.y, A[0][1]);
            A[0][2] = fmaf(xa.x, wb.z, A[0][2]); A[0][3] = fmaf(xa.x, wb.w, A[0][3]);
            A[1][0] = fmaf(xa.y, wb.x, A[1][0]); A[1][1] = fmaf(xa.y, wb.y, A[1][1]);
            A[1][2] = fmaf(xa.y, wb.z, A[1][2]); A[1][3] = fmaf(xa.y, wb.w, A[1][3]);
            A[2][0] = fmaf(xa.z, wb.x, A[2][0]); A[2][1] = fmaf(xa.z, wb.y, A[2][1]);
            A[2][2] = fmaf(xa.z, wb.z, A[2][2]); A[2][3] = fmaf(xa.z, wb.w, A[2][3]);
            A[3][0] = fmaf(xa.w, wb.x, A[3][0]); A[3][1] = fmaf(xa.w, wb.y, A[3][1]);
            A[3][2] = fmaf(xa.w, wb.z, A[3][2]); A[3][3] = fmaf(xa.w, wb.w, A[3][3]);
        }
    }
    #pragma unroll
    for (int i = 0; i < 4; ++i)
        #pragma unroll
        for (int j = 0; j < 4; ++j)
            sL[(mq << 2) + i][(nq << 2) + j] = a1[i][j] + a2[i][j];
    if (t < NE) hist[t] = 0;
    __syncthreads();
    if (t < 64) {
        const int m = t;
        float mx = sL[m][0]; int arg = 0;
        for (int e = 1; e < NE; ++e) { float v = sL[m][e]; if (v > mx) { mx = v; arg = e; } }
        float s = 0.f;
        for (int e = 0; e < NE; ++e) s += expf(sL[m][e] - mx);
        float inv = 1.f / s;
        out[m0 + m] = (float)arg; out[Ntok + m0 + m] = inv;
        smax[m] = mx; sinv[m] = inv;
        atomicAdd(&hist[arg], 1);
        float lse = mx + logf(s); float z = lse * lse;
        for (int off = 32; off > 0; off >>= 1) z += __shfl_down(z, off, 64);
        if (t == 0) ws_z[b] = z;
    }
    __syncthreads();
    {
        const int e = t & 63, mg = t >> 6;
        float pa = 0.f;
        for (int m = mg * 16; m < mg * 16 + 16; ++m) pa += expf(sL[m][e] - smax[m]) * sinv[m];
        spart[mg][e] = pa;
    }
    __syncthreads();
    if (t < NE) {
        ws_prob[b * NE + t] = spart[0][t] + spart[1][t] + spart[2][t] + spart[3][t];
        ws_cnt[b * NE + t]  = hist[t];
    }
}

extern "C" void kernel_launch(void* const* d_in, const int* in_sizes, int n_in,
                              void* d_out, int out_size, void* d_ws, size_t ws_size,
                              hipStream_t stream)
{
    const float* x = (const float*)d_in[0];
    const float* W = (const float*)d_in[1];
    float* out = (float*)d_out;

    const int Ntok = in_sizes[0] / D_MODEL;          // 16384
    const int nblk = Ntok / TB;                      // 256

    const size_t wh_elems = (size_t)NE * D_MODEL;    // 131072 shorts each
    const size_t need = wh_elems * 2 * 2
                      + ((size_t)nblk * NE + nblk) * 4
                      + (size_t)nblk * NE * 4 + 1024;

    if ((Ntok % TB) == 0 && (nblk % 4) == 0 && ws_size >= need) {
        short* wsh     = (short*)d_ws;               // Wh [64][2048]
        short* wsl     = wsh + wh_elems;             // Wl
        float* ws_prob = (float*)(wsl + wh_elems);
        float* ws_z    = ws_prob + (size_t)nblk * NE;
        int*   ws_cnt  = (int*)(ws_z + nblk);

        wcvt_kernel<<<NE, 256, 0, stream>>>(W, wsh, wsl);
        router_fused<<<nblk, 256, 0, stream>>>(x, wsh, wsl, out,
                                               ws_prob, ws_z, ws_cnt, Ntok);
        router_final2<<<1, 256, 0, stream>>>(ws_prob, ws_z, ws_cnt, out, Ntok, nblk);
    } else {
        const int nb = Ntok / 64;
        float* ws_prob = (float*)d_ws;
        float* ws_z    = ws_prob + (size_t)nb * NE;
        int*   ws_cnt  = (int*)(ws_z + nb);
        router_main_fb<<<nb, 256, 0, stream>>>(x, W, out, ws_prob, ws_z, ws_cnt, Ntok);
        router_final2<<<1, 256, 0, stream>>>(ws_prob, ws_z, ws_cnt, out, Ntok, nb);
    }
}

// Round 14
// 61.724 us; speedup vs baseline: 1.0470x; 1.0470x over previous
//
#include <hip/hip_runtime.h>
#include <math.h>

#define D_MODEL 2048
#define NE      64
#define TB      64               // tokens per fused block
#define KSEG    1024             // K-half per wave-group (in-block split-K)
#define KC      128              // fp32 k per chunk
#define NCH     (KSEG / KC)      // 8 chunks per group
#define FB_KC   32
#define FB_NCH  (D_MODEL / FB_KC)

typedef _Float16 half8 __attribute__((ext_vector_type(8)));
typedef float    f32x4 __attribute__((ext_vector_type(4)));

// two-term split of one float into fp16 high+low at ext-vector slot J.
// Named vars + constant indices only (rule #20 — unions/arrays → scratch).
#define CVT1(F, HV, LV, J) do {                                               \
    float _f = (F);                                                           \
    _Float16 _h = (_Float16)_f;                                               \
    HV[J] = _h;                                                               \
    LV[J] = (_Float16)(_f - (float)_h);                                       \
} while (0)

// ---------------- W -> (Wh, Wl) fp16 split, scaled x64 (r12-proven) ---------
__global__ __launch_bounds__(256) void wcvt_kernel(
    const float* __restrict__ W, short* __restrict__ Wh, short* __restrict__ Wl)
{
    const int e = blockIdx.x, t = threadIdx.x, c = t * 8;
    const float* src = W + (size_t)e * D_MODEL + c;
    float4 v0 = *(const float4*)src;
    float4 v1 = *(const float4*)(src + 4);
    half8 hv, lv;
    CVT1(v0.x * 64.0f, hv, lv, 0); CVT1(v0.y * 64.0f, hv, lv, 1);
    CVT1(v0.z * 64.0f, hv, lv, 2); CVT1(v0.w * 64.0f, hv, lv, 3);
    CVT1(v1.x * 64.0f, hv, lv, 4); CVT1(v1.y * 64.0f, hv, lv, 5);
    CVT1(v1.z * 64.0f, hv, lv, 6); CVT1(v1.w * 64.0f, hv, lv, 7);
    *(half8*)(Wh + (size_t)e * D_MODEL + c) = hv;
    *(half8*)(Wl + (size_t)e * D_MODEL + c) = lv;
}

// ---------------- fused MFMA gemm (in-block split-K) + stats ----------------
// 512 thr: wave-group g in {0,1} handles K-half g*1024..+1024 in its own
// 64KB LDS half (128KB total) -> grid 256, 8 waves/CU = 2/SIMD (r13 had 1:
// phase serialization was the regression). Pipeline per group = r13-proven
// (depth-2 A prefetch, CVT1, swizzle, 4-mfma split). Group accs summed in
// LDS fixed-order (= r12's proven KS=2 chain). Stats in-block, 512-thr.
__global__ __launch_bounds__(512) void router_fused8(
    const float* __restrict__ x, const short* __restrict__ Whg,
    const short* __restrict__ Wlg, float* __restrict__ out,
    float* __restrict__ ws_prob, float* __restrict__ ws_z,
    int* __restrict__ ws_cnt, int Ntok)
{
    __shared__ __align__(16) char smem[131072];    // 2 x 64KB group halves

    const int t  = threadIdx.x;
    const int b  = blockIdx.x;
    const int m0 = b * TB;
    const int g  = t >> 8;                   // K-half group 0/1
    const int tg = t & 255;
    const int l  = tg & 63;
    const int wv = tg >> 6;                  // 0..3 within group
    const int k0 = g * KSEG;

    char* gb = smem + g * 65536;
    _Float16* Ah = (_Float16*)gb;            // [64][128] f16, swizzled
    _Float16* Al = (_Float16*)(gb + 16384);
    _Float16* Wh = (_Float16*)(gb + 32768);
    _Float16* Wl = (_Float16*)(gb + 49152);

    // stats region (aliases group-0 half after the MFMA loop)
    float (*sL)[NE + 1] = (float (*)[NE + 1])smem;            // 16640 B
    float (*red8)[8]    = (float (*)[8])(smem + 16640);       // 2 KB
    int   (*arg8)[8]    = (int (*)[8])(smem + 18688);         // 2 KB
    float* smax         = (float*)(smem + 20736);
    float* sinv         = (float*)(smem + 20992);
    float (*spart)[NE]  = (float (*)[NE])(smem + 21248);      // 2 KB
    int*   hist         = (int*)(smem + 23296);

    // staging map (r12/r13-proven): item i: row = i*16+srow, 16B slot sslt,
    // swizzled dest slot = sslt ^ (srow&7)
    const int srow  = tg >> 4;               // 0..15
    const int sslt  = tg & 15;
    const int soff0 = ((sslt ^ (srow & 7)) << 3);

    float4 paA0, paA1, paA2, paA3, paA4, paA5, paA6, paA7;   // A set even
    float4 paB0, paB1, paB2, paB3, paB4, paB5, paB6, paB7;   // A set odd
    uint4  pwh0, pwh1, pwh2, pwh3, pwl0, pwl1, pwl2, pwl3;   // W current

#define PRE_A(P0, P1, P2, P3, P4, P5, P6, P7, KB) do {                        \
    const float* _a0 = x + (size_t)(m0 +  0 + srow) * D_MODEL + (KB) + sslt * 8; \
    const float* _a1 = x + (size_t)(m0 + 16 + srow) * D_MODEL + (KB) + sslt * 8; \
    const float* _a2 = x + (size_t)(m0 + 32 + srow) * D_MODEL + (KB) + sslt * 8; \
    const float* _a3 = x + (size_t)(m0 + 48 + srow) * D_MODEL + (KB) + sslt * 8; \
    P0 = *(const float4*)_a0; P1 = *(const float4*)(_a0 + 4);                 \
    P2 = *(const float4*)_a1; P3 = *(const float4*)(_a1 + 4);                 \
    P4 = *(const float4*)_a2; P5 = *(const float4*)(_a2 + 4);                 \
    P6 = *(const float4*)_a3; P7 = *(const float4*)(_a3 + 4);                 \
} while (0)

#define PRE_W(KB) do {                                                        \
    const size_t _w0 = (size_t)( 0 + srow) * D_MODEL + (KB) + sslt * 8;       \
    const size_t _w1 = (size_t)(16 + srow) * D_MODEL + (KB) + sslt * 8;       \
    const size_t _w2 = (size_t)(32 + srow) * D_MODEL + (KB) + sslt * 8;       \
    const size_t _w3 = (size_t)(48 + srow) * D_MODEL + (KB) + sslt * 8;       \
    pwh0 = *(const uint4*)&Whg[_w0]; pwh1 = *(const uint4*)&Whg[_w1];         \
    pwh2 = *(const uint4*)&Whg[_w2]; pwh3 = *(const uint4*)&Whg[_w3];         \
    pwl0 = *(const uint4*)&Wlg[_w0]; pwl1 = *(const uint4*)&Wlg[_w1];         \
    pwl2 = *(const uint4*)&Wlg[_w2]; pwl3 = *(const uint4*)&Wlg[_w3];         \
} while (0)

#define STORE_ITEM(I, PA, PB, PWH, PWL) do {                                  \
    half8 _hv, _lv;                                                           \
    CVT1((PA).x * 8.0f, _hv, _lv, 0); CVT1((PA).y * 8.0f, _hv, _lv, 1);       \
    CVT1((PA).z * 8.0f, _hv, _lv, 2); CVT1((PA).w * 8.0f, _hv, _lv, 3);       \
    CVT1((PB).x * 8.0f, _hv, _lv, 4); CVT1((PB).y * 8.0f, _hv, _lv, 5);       \
    CVT1((PB).z * 8.0f, _hv, _lv, 6); CVT1((PB).w * 8.0f, _hv, _lv, 7);       \
    const int _off = ((I) * 16 + srow) * 128 + soff0;                         \
    *(half8*)&Ah[_off] = _hv;                                                 \
    *(half8*)&Al[_off] = _lv;                                                 \
    *(uint4*)&Wh[_off] = PWH;                                                 \
    *(uint4*)&Wl[_off] = PWL;                                                 \
} while (0)

#define STORE_SET(P0, P1, P2, P3, P4, P5, P6, P7) do {                        \
    STORE_ITEM(0, P0, P1, pwh0, pwl0);                                        \
    STORE_ITEM(1, P2, P3, pwh1, pwl1);                                        \
    STORE_ITEM(2, P4, P5, pwh2, pwl2);                                        \
    STORE_ITEM(3, P6, P7, pwh3, pwl3);                                        \
} while (0)

#define MFMA_PHASE() do {                                                     \
    const int arow = wv * 16 + (l & 15);                                      \
    const int rsw  = l & 7;                                                   \
    _Pragma("unroll")                                                         \
    for (int kq = 0; kq < 4; ++kq) {                                          \
        const int s    = kq * 4 + (l >> 4);                                   \
        const int aoff = arow * 128 + ((s ^ rsw) << 3);                       \
        half8 ah = *(const half8*)&Ah[aoff];                                  \
        half8 al = *(const half8*)&Al[aoff];                                  \
        _Pragma("unroll")                                                     \
        for (int n = 0; n < 4; ++n) {                                         \
            const int woff = (n * 16 + (l & 15)) * 128 + ((s ^ rsw) << 3);    \
            half8 wh = *(const half8*)&Wh[woff];                              \
            half8 wl = *(const half8*)&Wl[woff];                              \
            f32x4 a = (n == 0) ? acc0 : (n == 1) ? acc1 : (n == 2) ? acc2 : acc3; \
            a = __builtin_amdgcn_mfma_f32_16x16x32_f16(al, wl, a, 0, 0, 0);   \
            a = __builtin_amdgcn_mfma_f32_16x16x32_f16(al, wh, a, 0, 0, 0);   \
            a = __builtin_amdgcn_mfma_f32_16x16x32_f16(ah, wl, a, 0, 0, 0);   \
            a = __builtin_amdgcn_mfma_f32_16x16x32_f16(ah, wh, a, 0, 0, 0);   \
            if (n == 0) acc0 = a; else if (n == 1) acc1 = a;                  \
            else if (n == 2) acc2 = a; else acc3 = a;                         \
        }                                                                     \
    }                                                                         \
} while (0)

    f32x4 acc0 = {0.f,0.f,0.f,0.f}, acc1 = {0.f,0.f,0.f,0.f};
    f32x4 acc2 = {0.f,0.f,0.f,0.f}, acc3 = {0.f,0.f,0.f,0.f};

    // prologue: A chunks 0,1 (depth 2) + W chunk 0 of this group's K-half
    PRE_A(paA0, paA1, paA2, paA3, paA4, paA5, paA6, paA7, k0);
    PRE_W(k0);
    PRE_A(paB0, paB1, paB2, paB3, paB4, paB5, paB6, paB7, k0 + KC);

    for (int ch = 0; ch < NCH; ch += 2) {
        // ---- even chunk: A set-A, W(ch) ----
        __builtin_amdgcn_s_barrier();
        STORE_SET(paA0, paA1, paA2, paA3, paA4, paA5, paA6, paA7);
        asm volatile("s_waitcnt lgkmcnt(0)" ::: "memory");
        __builtin_amdgcn_s_barrier();
        if (ch + 1 < NCH) PRE_W(k0 + (ch + 1) * KC);      // W first (older)
        if (ch + 2 < NCH)
            PRE_A(paA0, paA1, paA2, paA3, paA4, paA5, paA6, paA7, k0 + (ch + 2) * KC);
        MFMA_PHASE();
        // ---- odd chunk: A set-B, W(ch+1) ----
        __builtin_amdgcn_s_barrier();
        STORE_SET(paB0, paB1, paB2, paB3, paB4, paB5, paB6, paB7);
        asm volatile("s_waitcnt lgkmcnt(0)" ::: "memory");
        __builtin_amdgcn_s_barrier();
        if (ch + 2 < NCH) PRE_W(k0 + (ch + 2) * KC);
        if (ch + 3 < NCH)
            PRE_A(paB0, paB1, paB2, paB3, paB4, paB5, paB6, paB7, k0 + (ch + 3) * KC);
        MFMA_PHASE();
    }

    // ---- combine group accs in LDS (fixed order: g0 + g1, then scale) ----
    __syncthreads();                          // all MFMA LDS reads retired
    const int rbase = wv * 16 + (l >> 4) * 4; // m89 D-layout (proven r11/12)
    const int col0  = l & 15;
    if (g == 1) {
        #pragma unroll
        for (int q = 0; q < 4; ++q) {
            sL[rbase + q][ 0 + col0] = acc0[q];
            sL[rbase + q][16 + col0] = acc1[q];
            sL[rbase + q][32 + col0] = acc2[q];
            sL[rbase + q][48 + col0] = acc3[q];
        }
    }
    __syncthreads();
    if (g == 0) {
        #pragma unroll
        for (int q = 0; q < 4; ++q) {
            sL[rbase + q][ 0 + col0] = (acc0[q] + sL[rbase + q][ 0 + col0]) * (1.0f / 512.0f);
            sL[rbase + q][16 + col0] = (acc1[q] + sL[rbase + q][16 + col0]) * (1.0f / 512.0f);
            sL[rbase + q][32 + col0] = (acc2[q] + sL[rbase + q][32 + col0]) * (1.0f / 512.0f);
            sL[rbase + q][48 + col0] = (acc3[q] + sL[rbase + q][48 + col0]) * (1.0f / 512.0f);
        }
    }
    if (t < NE) hist[t] = 0;
    __syncthreads();

    {   // argmax: 8 threads/token, 8 experts each (ascending -> first-max)
        const int m = t >> 3, qr = t & 7;
        float mx = -3.4e38f; int ag = qr * 8;
        #pragma unroll
        for (int k = 0; k < 8; ++k) {
            const int e = qr * 8 + k;
            float v = sL[m][e];
            if (v > mx) { mx = v; ag = e; }
        }
        red8[m][qr] = mx; arg8[m][qr] = ag;
    }
    __syncthreads();
    if (t < 64) {                             // combine ascending: first-max
        const int m = t;
        float mx = red8[m][0]; int ag = arg8[m][0];
        #pragma unroll
        for (int qr = 1; qr < 8; ++qr)
            if (red8[m][qr] > mx) { mx = red8[m][qr]; ag = arg8[m][qr]; }
        smax[m] = mx;
        out[m0 + m] = (float)ag;              // expert_index
        atomicAdd(&hist[ag], 1);
    }
    __syncthreads();
    {   // expsum: 8 threads/token
        const int m = t >> 3, qr = t & 7;
        const float mx = smax[m];
        float s = 0.f;
        #pragma unroll
        for (int k = 0; k < 8; ++k) s += expf(sL[m][qr * 8 + k] - mx);
        red8[m][qr] = s;
    }
    __syncthreads();
    if (t < 64) {
        const int m = t;
        float s = 0.f;
        #pragma unroll
        for (int qr = 0; qr < 8; ++qr) s += red8[m][qr];     // fixed order
        float inv = 1.f / s;
        sinv[m] = inv;
        out[Ntok + m0 + m] = inv;             // expert_prob
        float lse = smax[m] + logf(s);
        float z = lse * lse;
        #pragma unroll
        for (int off = 32; off > 0; off >>= 1) z += __shfl_down(z, off, 64);
        if (t == 0) ws_z[b] = z;
    }
    __syncthreads();
    {   // probsum: 8 waves, wave gw covers 8 tokens, lane = expert
        const int e = t & 63, gw = t >> 6;
        float pa = 0.f;
        #pragma unroll
        for (int k = 0; k < 8; ++k) {
            const int m = gw * 8 + k;
            pa += expf(sL[m][e] - smax[m]) * sinv[m];
        }
        spart[gw][e] = pa;
    }
    __syncthreads();
    if (t < NE) {
        float ps = 0.f;
        #pragma unroll
        for (int gw = 0; gw < 8; ++gw) ps += spart[gw][t];   // fixed order
        ws_prob[b * NE + t] = ps;
        ws_cnt[b * NE + t]  = hist[t];
    }
}

// ---------------- final reduce (r10/r12-proven) -----------------------------
__global__ __launch_bounds__(256) void router_final2(
    const float* __restrict__ ws_prob, const float* __restrict__ ws_z,
    const int* __restrict__ ws_cnt, float* __restrict__ out,
    int Ntok, int nblocks)
{
    __shared__ float sp[4][NE];
    __shared__ int   sc[4][NE];
    __shared__ float sz[4];

    const int e = threadIdx.x & 63, g = threadIdx.x >> 6;
    const int per = nblocks / 4;
    const int hi  = (g == 3) ? nblocks : (g + 1) * per;

    float ps = 0.f; int c = 0;
    for (int blk = g * per; blk < hi; ++blk) {       // fixed partition
        ps += ws_prob[blk * NE + e];
        c  += ws_cnt[blk * NE + e];
    }
    sp[g][e] = ps; sc[g][e] = c;

    float z = 0.f;
    for (int blk = (int)threadIdx.x; blk < nblocks; blk += 256) z += ws_z[blk];
    #pragma unroll
    for (int off = 32; off > 0; off >>= 1) z += __shfl_down(z, off, 64);
    if (e == 0) sz[g] = z;
    __syncthreads();

    if (threadIdx.x < 64) {
        const int ee = threadIdx.x;
        float pst = ((sp[0][ee] + sp[1][ee]) + sp[2][ee]) + sp[3][ee];
        int   ct  = ((sc[0][ee] + sc[1][ee]) + sc[2][ee]) + sc[3][ee];
        out[2 * Ntok + ee] = (float)ct;              // counts

        float fN = (float)Ntok;
        float fp = ((float)ct / fN) * (pst / fN);
        #pragma unroll
        for (int off = 32; off > 0; off >>= 1) fp += __shfl_down(fp, off, 64);
        if (ee == 0) {
            float zt = ((sz[0] + sz[1]) + sz[2]) + sz[3];
            int cap = (Ntok + NE - 1) / NE;
            if (cap < 4) cap = 4;
            float aux = 0.01f * (float)NE * fp + 1e-3f * (zt / fN);
            out[2 * Ntok + NE]     = (float)cap;     // capacity
            out[2 * Ntok + NE + 1] = aux;            // aux_loss
        }
    }
}

// ---------------- fallback (round-1 proven fused fp32 path) -----------------
__global__ __launch_bounds__(256) void router_main_fb(
    const float* __restrict__ x, const float* __restrict__ W,
    float* __restrict__ out, float* __restrict__ ws_prob,
    float* __restrict__ ws_z, int* __restrict__ ws_cnt, int Ntok)
{
    __shared__ __align__(16) float sX[FB_KC][68];
    __shared__ __align__(16) float sW[FB_KC][68];
    __shared__ float sL[64][65];
    __shared__ float smax[64], sinv[64];
    __shared__ float spart[4][NE];
    __shared__ int   hist[NE];

    const int t = threadIdx.x, b = blockIdx.x, m0 = b * 64;
    const int mq = t & 15, nq = t >> 4;
    const int r1 = t >> 3, r2 = r1 + 32, c1 = (t & 7) << 2;
    const float* xp1 = x + (size_t)(m0 + r1) * D_MODEL + c1;
    const float* xp2 = x + (size_t)(m0 + r2) * D_MODEL + c1;
    const float* wp1 = W + (size_t)r1 * D_MODEL + c1;
    const float* wp2 = W + (size_t)r2 * D_MODEL + c1;
    float4 ax1 = *(const float4*)xp1, ax2 = *(const float4*)xp2;
    float4 aw1 = *(const float4*)wp1, aw2 = *(const float4*)wp2;
    float a1[4][4] = {}, a2[4][4] = {};
    for (int ch = 0; ch < FB_NCH; ++ch) {
        __syncthreads();
        sX[c1+0][r1] = ax1.x; sX[c1+1][r1] = ax1.y; sX[c1+2][r1] = ax1.z; sX[c1+3][r1] = ax1.w;
        sX[c1+0][r2] = ax2.x; sX[c1+1][r2] = ax2.y; sX[c1+2][r2] = ax2.z; sX[c1+3][r2] = ax2.w;
        sW[c1+0][r1] = aw1.x; sW[c1+1][r1] = aw1.y; sW[c1+2][r1] = aw1.z; sW[c1+3][r1] = aw1.w;
        sW[c1+0][r2] = aw2.x; sW[c1+1][r2] = aw2.y; sW[c1+2][r2] = aw2.z; sW[c1+3][r2] = aw2.w;
        __syncthreads();
        if (ch + 1 < FB_NCH) {
            xp1 += FB_KC; xp2 += FB_KC; wp1 += FB_KC; wp2 += FB_KC;
            ax1 = *(const float4*)xp1; ax2 = *(const float4*)xp2;
            aw1 = *(const float4*)wp1; aw2 = *(const float4*)wp2;
        }
        #pragma unroll
        for (int k = 0; k < FB_KC; ++k) {
            float4 xa = *(const float4*)&sX[k][mq << 2];
            float4 wb = *(const float4*)&sW[k][nq << 2];
            float (*A)[4] = (k < FB_KC / 2) ? a1 : a2;
            A[0][0] = fmaf(xa.x, wb.x, A[0][0]); A[0][1] = fmaf(xa.x, wb.y, A[0][1]);
            A[0][2] = fmaf(xa.x, wb.z, A[0][2]); A[0][3] = fmaf(xa.x, wb.w, A[0][3]);
            A[1][0] = fmaf(xa.y, wb.x, A[1][0]); A[1][1] = fmaf(xa.y, wb.y, A[1][1]);
            A[1][2] = fmaf(xa.y, wb.z, A[1][2]); A[1][3] = fmaf(xa.y, wb.w, A[1][3]);
            A[2][0] = fmaf(xa.z, wb.x, A[2][0]); A[2][1] = fmaf(xa.z, wb.y, A[2][1]);
            A[2][2] = fmaf(xa.z, wb.z, A[2][2]); A[2][3] = fmaf(xa.z, wb.w, A[2][3]);
            A[3][0] = fmaf(xa.w, wb.x, A[3][0]); A[3][1] = fmaf(xa.w, wb.y, A[3][1]);
            A[3][2] = fmaf(xa.w, wb.z, A[3][2]); A[3][3] = fmaf(xa.w, wb.w, A[3][3]);
        }
    }
    #pragma unroll
    for (int i = 0; i < 4; ++i)
        #pragma unroll
        for (int j = 0; j < 4; ++j)
            sL[(mq << 2) + i][(nq << 2) + j] = a1[i][j] + a2[i][j];
    if (t < NE) hist[t] = 0;
    __syncthreads();
    if (t < 64) {
        const int m = t;
        float mx = sL[m][0]; int arg = 0;
        for (int e = 1; e < NE; ++e) { float v = sL[m][e]; if (v > mx) { mx = v; arg = e; } }
        float s = 0.f;
        for (int e = 0; e < NE; ++e) s += expf(sL[m][e] - mx);
        float inv = 1.f / s;
        out[m0 + m] = (float)arg; out[Ntok + m0 + m] = inv;
        smax[m] = mx; sinv[m] = inv;
        atomicAdd(&hist[arg], 1);
        float lse = mx + logf(s); float z = lse * lse;
        for (int off = 32; off > 0; off >>= 1) z += __shfl_down(z, off, 64);
        if (t == 0) ws_z[b] = z;
    }
    __syncthreads();
    {
        const int e = t & 63, mg = t >> 6;
        float pa = 0.f;
        for (int m = mg * 16; m < mg * 16 + 16; ++m) pa += expf(sL[m][e] - smax[m]) * sinv[m];
        spart[mg][e] = pa;
    }
    __syncthreads();
    if (t < NE) {
        ws_prob[b * NE + t] = spart[0][t] + spart[1][t] + spart[2][t] + spart[3][t];
        ws_cnt[b * NE + t]  = hist[t];
    }
}

extern "C" void kernel_launch(void* const* d_in, const int* in_sizes, int n_in,
                              void* d_out, int out_size, void* d_ws, size_t ws_size,
                              hipStream_t stream)
{
    const float* x = (const float*)d_in[0];
    const float* W = (const float*)d_in[1];
    float* out = (float*)d_out;

    const int Ntok = in_sizes[0] / D_MODEL;          // 16384
    const int nblk = Ntok / TB;                      // 256

    const size_t wh_elems = (size_t)NE * D_MODEL;    // 131072 shorts each
    const size_t need = wh_elems * 2 * 2
                      + ((size_t)nblk * NE + nblk) * 4
                      + (size_t)nblk * NE * 4 + 1024;

    if ((Ntok % TB) == 0 && (nblk % 4) == 0 && ws_size >= need) {
        short* wsh     = (short*)d_ws;               // Wh [64][2048]
        short* wsl     = wsh + wh_elems;             // Wl
        float* ws_prob = (float*)(wsl + wh_elems);
        float* ws_z    = ws_prob + (size_t)nblk * NE;
        int*   ws_cnt  = (int*)(ws_z + nblk);

        wcvt_kernel<<<NE, 256, 0, stream>>>(W, wsh, wsl);
        router_fused8<<<nblk, 512, 0, stream>>>(x, wsh, wsl, out,
                                                ws_prob, ws_z, ws_cnt, Ntok);
        router_final2<<<1, 256, 0, stream>>>(ws_prob, ws_z, ws_cnt, out, Ntok, nblk);
    } else {
        const int nb = Ntok / 64;
        float* ws_prob = (float*)d_ws;
        float* ws_z    = ws_prob + (size_t)nb * NE;
        int*   ws_cnt  = (int*)(ws_z + nb);
        router_main_fb<<<nb, 256, 0, stream>>>(x, W, out, ws_prob, ws_z, ws_cnt, Ntok);
        router_final2<<<1, 256, 0, stream>>>(ws_prob, ws_z, ws_cnt, out, Ntok, nb);
    }
}

// Round 16
// 59.612 us; speedup vs baseline: 1.0841x; 1.0354x over previous
//
#include <hip/hip_runtime.h>
#include <math.h>

#define D_MODEL 2048
#define NE      64
#define TB      64               // tokens per fused block
#define KSEG    1024             // K-half per wave-group (in-block split-K)
#define KC      64               // fp32 k per chunk
#define NCH     (KSEG / KC)      // 16 chunks per group
#define FB_KC   32
#define FB_NCH  (D_MODEL / FB_KC)

typedef _Float16 half8 __attribute__((ext_vector_type(8)));
typedef float    f32x4 __attribute__((ext_vector_type(4)));

// two-term split of one float into fp16 high+low at ext-vector slot J.
// Named vars + constant indices only (rule #20 — unions/arrays → scratch).
#define CVT1(F, HV, LV, J) do {                                               \
    float _f = (F);                                                           \
    _Float16 _h = (_Float16)_f;                                               \
    HV[J] = _h;                                                               \
    LV[J] = (_Float16)(_f - (float)_h);                                       \
} while (0)

// ---------------- W -> (Wh, Wl) fp16 split, scaled x64 (r12-proven) ---------
__global__ __launch_bounds__(256) void wcvt_kernel(
    const float* __restrict__ W, short* __restrict__ Wh, short* __restrict__ Wl)
{
    const int e = blockIdx.x, t = threadIdx.x, c = t * 8;
    const float* src = W + (size_t)e * D_MODEL + c;
    float4 v0 = *(const float4*)src;
    float4 v1 = *(const float4*)(src + 4);
    half8 hv, lv;
    CVT1(v0.x * 64.0f, hv, lv, 0); CVT1(v0.y * 64.0f, hv, lv, 1);
    CVT1(v0.z * 64.0f, hv, lv, 2); CVT1(v0.w * 64.0f, hv, lv, 3);
    CVT1(v1.x * 64.0f, hv, lv, 4); CVT1(v1.y * 64.0f, hv, lv, 5);
    CVT1(v1.z * 64.0f, hv, lv, 6); CVT1(v1.w * 64.0f, hv, lv, 7);
    *(half8*)(Wh + (size_t)e * D_MODEL + c) = hv;
    *(half8*)(Wl + (size_t)e * D_MODEL + c) = lv;
}

// ---------------- fused MFMA gemm, dbuf LDS, 1 barrier/chunk ----------------
// 512 thr, 2 wave-groups x K-half (r14). NEW: per group 2x32KB LDS buffers;
// each chunk: PRE(ch+2) || STORE(ch+1 -> other buf) || MFMA(cur buf), then
// ONE lgkmcnt(0)+s_barrier. Store/cvt/loads co-schedule with MFMA (separate
// pipes, m114) — removes the r13/r14 phase convoy. Accumulation order
// bit-identical to r14 (same ascending-k 4-term chain) -> same absmax.
__global__ __launch_bounds__(512) void router_fused_db(
    const float* __restrict__ x, const short* __restrict__ Whg,
    const short* __restrict__ Wlg, float* __restrict__ out,
    float* __restrict__ ws_prob, float* __restrict__ ws_z,
    int* __restrict__ ws_cnt, int Ntok)
{
    __shared__ __align__(16) char smem[131072];   // 2 groups x 2 bufs x 32KB

    const int t  = threadIdx.x;
    const int b  = blockIdx.x;
    const int m0 = b * TB;
    const int g  = t >> 8;                   // K-half group 0/1
    const int tg = t & 255;
    const int l  = tg & 63;
    const int wv = tg >> 6;                  // 0..3 within group
    const int k0 = g * KSEG;

    // buf base: group g, buffer bb -> smem + g*65536 + bb*32768
    // within buf: Ah @0 (8KB), Al @8KB, Wh @16KB, Wl @24KB; rows of 64 halves
    char* gbase = smem + g * 65536;

    // stats region (aliases group-0 half after the MFMA loop)
    float (*sL)[NE + 1] = (float (*)[NE + 1])smem;            // 16640 B
    float (*red8)[8]    = (float (*)[8])(smem + 16640);       // 2 KB
    int   (*arg8)[8]    = (int (*)[8])(smem + 18688);         // 2 KB
    float* smax         = (float*)(smem + 20736);
    float* sinv         = (float*)(smem + 20992);
    float (*spart)[NE]  = (float (*)[NE])(smem + 21248);      // 2 KB
    int*   hist         = (int*)(smem + 23296);

    // staging map: srow = row/expert (0..63), sc = 16-half column group (0..3)
    const int srow = tg >> 2;
    const int sc   = tg & 3;
    const int ssw  = srow & 7;
    const int sof0 = (srow << 6) + (((sc * 2 + 0) ^ ssw) << 3);  // halves
    const int sof1 = (srow << 6) + (((sc * 2 + 1) ^ ssw) << 3);

    float4 aA0, aA1, aA2, aA3;               // A set even (16 floats)
    float4 aB0, aB1, aB2, aB3;               // A set odd
    uint4  whA0, whA1, wlA0, wlA1;           // W set even (16+16 halves)
    uint4  whB0, whB1, wlB0, wlB1;           // W set odd

#define PRE_SET(A0, A1, A2, A3, WH0, WH1, WL0, WL1, KB) do {                  \
    const float* _ap = x + (size_t)(m0 + srow) * D_MODEL + (KB) + sc * 16;    \
    A0 = *(const float4*)_ap;       A1 = *(const float4*)(_ap + 4);           \
    A2 = *(const float4*)(_ap + 8); A3 = *(const float4*)(_ap + 12);          \
    const size_t _wr = (size_t)srow * D_MODEL + (KB) + sc * 16;               \
    WH0 = *(const uint4*)&Whg[_wr]; WH1 = *(const uint4*)&Whg[_wr + 8];       \
    WL0 = *(const uint4*)&Wlg[_wr]; WL1 = *(const uint4*)&Wlg[_wr + 8];       \
} while (0)

#define STORE_SET(A0, A1, A2, A3, WH0, WH1, WL0, WL1, BB) do {                \
    _Float16* _Ah = (_Float16*)(gbase + (BB) * 32768);                        \
    _Float16* _Al = (_Float16*)(gbase + (BB) * 32768 + 8192);                 \
    _Float16* _Wh = (_Float16*)(gbase + (BB) * 32768 + 16384);                \
    _Float16* _Wl = (_Float16*)(gbase + (BB) * 32768 + 24576);                \
    half8 _h0, _l0, _h1, _l1;                                                 \
    CVT1((A0).x * 8.0f, _h0, _l0, 0); CVT1((A0).y * 8.0f, _h0, _l0, 1);       \
    CVT1((A0).z * 8.0f, _h0, _l0, 2); CVT1((A0).w * 8.0f, _h0, _l0, 3);       \
    CVT1((A1).x * 8.0f, _h0, _l0, 4); CVT1((A1).y * 8.0f, _h0, _l0, 5);       \
    CVT1((A1).z * 8.0f, _h0, _l0, 6); CVT1((A1).w * 8.0f, _h0, _l0, 7);       \
    CVT1((A2).x * 8.0f, _h1, _l1, 0); CVT1((A2).y * 8.0f, _h1, _l1, 1);       \
    CVT1((A2).z * 8.0f, _h1, _l1, 2); CVT1((A2).w * 8.0f, _h1, _l1, 3);       \
    CVT1((A3).x * 8.0f, _h1, _l1, 4); CVT1((A3).y * 8.0f, _h1, _l1, 5);       \
    CVT1((A3).z * 8.0f, _h1, _l1, 6); CVT1((A3).w * 8.0f, _h1, _l1, 7);       \
    *(half8*)&_Ah[sof0] = _h0;  *(half8*)&_Ah[sof1] = _h1;                    \
    *(half8*)&_Al[sof0] = _l0;  *(half8*)&_Al[sof1] = _l1;                    \
    *(uint4*)&_Wh[sof0] = WH0;  *(uint4*)&_Wh[sof1] = WH1;                    \
    *(uint4*)&_Wl[sof0] = WL0;  *(uint4*)&_Wl[sof1] = WL1;                    \
} while (0)

#define MFMA_PHASE(BB) do {                                                   \
    const _Float16* _Ah = (const _Float16*)(gbase + (BB) * 32768);            \
    const _Float16* _Al = (const _Float16*)(gbase + (BB) * 32768 + 8192);     \
    const _Float16* _Wh = (const _Float16*)(gbase + (BB) * 32768 + 16384);    \
    const _Float16* _Wl = (const _Float16*)(gbase + (BB) * 32768 + 24576);    \
    const int arow = wv * 16 + (l & 15);                                      \
    const int rsw  = l & 7;                                                   \
    _Pragma("unroll")                                                         \
    for (int kq = 0; kq < 2; ++kq) {                                          \
        const int s    = kq * 4 + (l >> 4);                                   \
        const int aoff = arow * 64 + ((s ^ rsw) << 3);                        \
        half8 ah = *(const half8*)&_Ah[aoff];                                 \
        half8 al = *(const half8*)&_Al[aoff];                                 \
        _Pragma("unroll")                                                     \
        for (int n = 0; n < 4; ++n) {                                         \
            const int woff = (n * 16 + (l & 15)) * 64 + ((s ^ rsw) << 3);     \
            half8 wh = *(const half8*)&_Wh[woff];                             \
            half8 wl = *(const half8*)&_Wl[woff];                             \
            f32x4 a = (n == 0) ? acc0 : (n == 1) ? acc1 : (n == 2) ? acc2 : acc3; \
            a = __builtin_amdgcn_mfma_f32_16x16x32_f16(al, wl, a, 0, 0, 0);   \
            a = __builtin_amdgcn_mfma_f32_16x16x32_f16(al, wh, a, 0, 0, 0);   \
            a = __builtin_amdgcn_mfma_f32_16x16x32_f16(ah, wl, a, 0, 0, 0);   \
            a = __builtin_amdgcn_mfma_f32_16x16x32_f16(ah, wh, a, 0, 0, 0);   \
            if (n == 0) acc0 = a; else if (n == 1) acc1 = a;                  \
            else if (n == 2) acc2 = a; else acc3 = a;                         \
        }                                                                     \
    }                                                                         \
} while (0)

    f32x4 acc0 = {0.f,0.f,0.f,0.f}, acc1 = {0.f,0.f,0.f,0.f};
    f32x4 acc2 = {0.f,0.f,0.f,0.f}, acc3 = {0.f,0.f,0.f,0.f};

    // prologue: regs for chunks 0,1; store chunk 0 into buf 0
    PRE_SET(aA0, aA1, aA2, aA3, whA0, whA1, wlA0, wlA1, k0);
    PRE_SET(aB0, aB1, aB2, aB3, whB0, whB1, wlB0, wlB1, k0 + KC);
    STORE_SET(aA0, aA1, aA2, aA3, whA0, whA1, wlA0, wlA1, 0);
    asm volatile("s_waitcnt lgkmcnt(0)" ::: "memory");
    __builtin_amdgcn_s_barrier();

    for (int ch = 0; ch < NCH; ch += 2) {
        // even chunk: MFMA(buf0) || STORE(setB->buf1) || PRE(setA, ch+2)
        if (ch + 2 < NCH)
            PRE_SET(aA0, aA1, aA2, aA3, whA0, whA1, wlA0, wlA1, k0 + (ch + 2) * KC);
        if (ch + 1 < NCH)
            STORE_SET(aB0, aB1, aB2, aB3, whB0, whB1, wlB0, wlB1, 1);
        MFMA_PHASE(0);
        asm volatile("s_waitcnt lgkmcnt(0)" ::: "memory");
        __builtin_amdgcn_s_barrier();
        // odd chunk: MFMA(buf1) || STORE(setA->buf0) || PRE(setB, ch+3)
        if (ch + 3 < NCH)
            PRE_SET(aB0, aB1, aB2, aB3, whB0, whB1, wlB0, wlB1, k0 + (ch + 3) * KC);
        if (ch + 2 < NCH)
            STORE_SET(aA0, aA1, aA2, aA3, whA0, whA1, wlA0, wlA1, 0);
        MFMA_PHASE(1);
        asm volatile("s_waitcnt lgkmcnt(0)" ::: "memory");
        __builtin_amdgcn_s_barrier();
    }

    // ---- combine group accs in LDS (fixed order: g0 + g1, then scale) ----
    __syncthreads();                          // all MFMA LDS reads retired
    const int rbase = wv * 16 + (l >> 4) * 4; // m89 D-layout (proven r11/12)
    const int col0  = l & 15;
    if (g == 1) {
        #pragma unroll
        for (int q = 0; q < 4; ++q) {
            sL[rbase + q][ 0 + col0] = acc0[q];
            sL[rbase + q][16 + col0] = acc1[q];
            sL[rbase + q][32 + col0] = acc2[q];
            sL[rbase + q][48 + col0] = acc3[q];
        }
    }
    __syncthreads();
    if (g == 0) {
        #pragma unroll
        for (int q = 0; q < 4; ++q) {
            sL[rbase + q][ 0 + col0] = (acc0[q] + sL[rbase + q][ 0 + col0]) * (1.0f / 512.0f);
            sL[rbase + q][16 + col0] = (acc1[q] + sL[rbase + q][16 + col0]) * (1.0f / 512.0f);
            sL[rbase + q][32 + col0] = (acc2[q] + sL[rbase + q][32 + col0]) * (1.0f / 512.0f);
            sL[rbase + q][48 + col0] = (acc3[q] + sL[rbase + q][48 + col0]) * (1.0f / 512.0f);
        }
    }
    if (t < NE) hist[t] = 0;
    __syncthreads();

    {   // argmax: 8 threads/token, 8 experts each (ascending -> first-max)
        const int m = t >> 3, qr = t & 7;
        float mx = -3.4e38f; int ag = qr * 8;
        #pragma unroll
        for (int k = 0; k < 8; ++k) {
            const int e = qr * 8 + k;
            float v = sL[m][e];
            if (v > mx) { mx = v; ag = e; }
        }
        red8[m][qr] = mx; arg8[m][qr] = ag;
    }
    __syncthreads();
    if (t < 64) {                             // combine ascending: first-max
        const int m = t;
        float mx = red8[m][0]; int ag = arg8[m][0];
        #pragma unroll
        for (int qr = 1; qr < 8; ++qr)
            if (red8[m][qr] > mx) { mx = red8[m][qr]; ag = arg8[m][qr]; }
        smax[m] = mx;
        out[m0 + m] = (float)ag;              // expert_index
        atomicAdd(&hist[ag], 1);
    }
    __syncthreads();
    {   // expsum: 8 threads/token
        const int m = t >> 3, qr = t & 7;
        const float mx = smax[m];
        float s = 0.f;
        #pragma unroll
        for (int k = 0; k < 8; ++k) s += expf(sL[m][qr * 8 + k] - mx);
        red8[m][qr] = s;
    }
    __syncthreads();
    if (t < 64) {
        const int m = t;
        float s = 0.f;
        #pragma unroll
        for (int qr = 0; qr < 8; ++qr) s += red8[m][qr];     // fixed order
        float inv = 1.f / s;
        sinv[m] = inv;
        out[Ntok + m0 + m] = inv;             // expert_prob
        float lse = smax[m] + logf(s);
        float z = lse * lse;
        #pragma unroll
        for (int off = 32; off > 0; off >>= 1) z += __shfl_down(z, off, 64);
        if (t == 0) ws_z[b] = z;
    }
    __syncthreads();
    {   // probsum: 8 waves, wave gw covers 8 tokens, lane = expert
        const int e = t & 63, gw = t >> 6;
        float pa = 0.f;
        #pragma unroll
        for (int k = 0; k < 8; ++k) {
            const int m = gw * 8 + k;
            pa += expf(sL[m][e] - smax[m]) * sinv[m];
        }
        spart[gw][e] = pa;
    }
    __syncthreads();
    if (t < NE) {
        float ps = 0.f;
        #pragma unroll
        for (int gw = 0; gw < 8; ++gw) ps += spart[gw][t];   // fixed order
        ws_prob[b * NE + t] = ps;
        ws_cnt[b * NE + t]  = hist[t];
    }
}

// ---------------- final reduce (r10/r12-proven) -----------------------------
__global__ __launch_bounds__(256) void router_final2(
    const float* __restrict__ ws_prob, const float* __restrict__ ws_z,
    const int* __restrict__ ws_cnt, float* __restrict__ out,
    int Ntok, int nblocks)
{
    __shared__ float sp[4][NE];
    __shared__ int   sc[4][NE];
    __shared__ float sz[4];

    const int e = threadIdx.x & 63, g = threadIdx.x >> 6;
    const int per = nblocks / 4;
    const int hi  = (g == 3) ? nblocks : (g + 1) * per;

    float ps = 0.f; int c = 0;
    for (int blk = g * per; blk < hi; ++blk) {       // fixed partition
        ps += ws_prob[blk * NE + e];
        c  += ws_cnt[blk * NE + e];
    }
    sp[g][e] = ps; sc[g][e] = c;

    float z = 0.f;
    for (int blk = (int)threadIdx.x; blk < nblocks; blk += 256) z += ws_z[blk];
    #pragma unroll
    for (int off = 32; off > 0; off >>= 1) z += __shfl_down(z, off, 64);
    if (e == 0) sz[g] = z;
    __syncthreads();

    if (threadIdx.x < 64) {
        const int ee = threadIdx.x;
        float pst = ((sp[0][ee] + sp[1][ee]) + sp[2][ee]) + sp[3][ee];
        int   ct  = ((sc[0][ee] + sc[1][ee]) + sc[2][ee]) + sc[3][ee];
        out[2 * Ntok + ee] = (float)ct;              // counts

        float fN = (float)Ntok;
        float fp = ((float)ct / fN) * (pst / fN);
        #pragma unroll
        for (int off = 32; off > 0; off >>= 1) fp += __shfl_down(fp, off, 64);
        if (ee == 0) {
            float zt = ((sz[0] + sz[1]) + sz[2]) + sz[3];
            int cap = (Ntok + NE - 1) / NE;
            if (cap < 4) cap = 4;
            float aux = 0.01f * (float)NE * fp + 1e-3f * (zt / fN);
            out[2 * Ntok + NE]     = (float)cap;     // capacity
            out[2 * Ntok + NE + 1] = aux;            // aux_loss
        }
    }
}

// ---------------- fallback (round-1 proven fused fp32 path) -----------------
__global__ __launch_bounds__(256) void router_main_fb(
    const float* __restrict__ x, const float* __restrict__ W,
    float* __restrict__ out, float* __restrict__ ws_prob,
    float* __restrict__ ws_z, int* __restrict__ ws_cnt, int Ntok)
{
    __shared__ __align__(16) float sX[FB_KC][68];
    __shared__ __align__(16) float sW[FB_KC][68];
    __shared__ float sL[64][65];
    __shared__ float smax[64], sinv[64];
    __shared__ float spart[4][NE];
    __shared__ int   hist[NE];

    const int t = threadIdx.x, b = blockIdx.x, m0 = b * 64;
    const int mq = t & 15, nq = t >> 4;
    const int r1 = t >> 3, r2 = r1 + 32, c1 = (t & 7) << 2;
    const float* xp1 = x + (size_t)(m0 + r1) * D_MODEL + c1;
    const float* xp2 = x + (size_t)(m0 + r2) * D_MODEL + c1;
    const float* wp1 = W + (size_t)r1 * D_MODEL + c1;
    const float* wp2 = W + (size_t)r2 * D_MODEL + c1;
    float4 ax1 = *(const float4*)xp1, ax2 = *(const float4*)xp2;
    float4 aw1 = *(const float4*)wp1, aw2 = *(const float4*)wp2;
    float a1[4][4] = {}, a2[4][4] = {};
    for (int ch = 0; ch < FB_NCH; ++ch) {
        __syncthreads();
        sX[c1+0][r1] = ax1.x; sX[c1+1][r1] = ax1.y; sX[c1+2][r1] = ax1.z; sX[c1+3][r1] = ax1.w;
        sX[c1+0][r2] = ax2.x; sX[c1+1][r2] = ax2.y; sX[c1+2][r2] = ax2.z; sX[c1+3][r2] = ax2.w;
        sW[c1+0][r1] = aw1.x; sW[c1+1][r1] = aw1.y; sW[c1+2][r1] = aw1.z; sW[c1+3][r1] = aw1.w;
        sW[c1+0][r2] = aw2.x; sW[c1+1][r2] = aw2.y; sW[c1+2][r2] = aw2.z; sW[c1+3][r2] = aw2.w;
        __syncthreads();
        if (ch + 1 < FB_NCH) {
            xp1 += FB_KC; xp2 += FB_KC; wp1 += FB_KC; wp2 += FB_KC;
            ax1 = *(const float4*)xp1; ax2 = *(const float4*)xp2;
            aw1 = *(const float4*)wp1; aw2 = *(const float4*)wp2;
        }
        #pragma unroll
        for (int k = 0; k < FB_KC; ++k) {
            float4 xa = *(const float4*)&sX[k][mq << 2];
            float4 wb = *(const float4*)&sW[k][nq << 2];
            float (*A)[4] = (k < FB_KC / 2) ? a1 : a2;
            A[0][0] = fmaf(xa.x, wb.x, A[0][0]); A[0][1] = fmaf(xa.x, wb.y, A[0][1]);
            A[0][2] = fmaf(xa.x, wb.z, A[0][2]); A[0][3] = fmaf(xa.x, wb.w, A[0][3]);
            A[1][0] = fmaf(xa.y, wb.x, A[1][0]); A[1][1] = fmaf(xa.y, wb.y, A[1][1]);
            A[1][2] = fmaf(xa.y, wb.z, A[1][2]); A[1][3] = fmaf(xa.y, wb.w, A[1][3]);
            A[2][0] = fmaf(xa.z, wb.x, A[2][0]); A[2][1] = fmaf(xa.z, wb.y, A[2][1]);
            A[2][2] = fmaf(xa.z, wb.z, A[2][2]); A[2][3] = fmaf(xa.z, wb.w, A[2][3]);
            A[3][0] = fmaf(xa.w, wb.x, A[3][0]); A[3][1] = fmaf(xa.w, wb.y, A[3][1]);
            A[3][2] = fmaf(xa.w, wb.z, A[3][2]); A[3][3] = fmaf(xa.w, wb.w, A[3][3]);
        }
    }
    #pragma unroll
    for (int i = 0; i < 4; ++i)
        #pragma unroll
        for (int j = 0; j < 4; ++j)
            sL[(mq << 2) + i][(nq << 2) + j] = a1[i][j] + a2[i][j];
    if (t < NE) hist[t] = 0;
    __syncthreads();
    if (t < 64) {
        const int m = t;
        float mx = sL[m][0]; int arg = 0;
        for (int e = 1; e < NE; ++e) { float v = sL[m][e]; if (v > mx) { mx = v; arg = e; } }
        float s = 0.f;
        for (int e = 0; e < NE; ++e) s += expf(sL[m][e] - mx);
        float inv = 1.f / s;
        out[m0 + m] = (float)arg; out[Ntok + m0 + m] = inv;
        smax[m] = mx; sinv[m] = inv;
        atomicAdd(&hist[arg], 1);
        float lse = mx + logf(s); float z = lse * lse;
        for (int off = 32; off > 0; off >>= 1) z += __shfl_down(z, off, 64);
        if (t == 0) ws_z[b] = z;
    }
    __syncthreads();
    {
        const int e = t & 63, mg = t >> 6;
        float pa = 0.f;
        for (int m = mg * 16; m < mg * 16 + 16; ++m) pa += expf(sL[m][e] - smax[m]) * sinv[m];
        spart[mg][e] = pa;
    }
    __syncthreads();
    if (t < NE) {
        ws_prob[b * NE + t] = spart[0][t] + spart[1][t] + spart[2][t] + spart[3][t];
        ws_cnt[b * NE + t]  = hist[t];
    }
}

extern "C" void kernel_launch(void* const* d_in, const int* in_sizes, int n_in,
                              void* d_out, int out_size, void* d_ws, size_t ws_size,
                              hipStream_t stream)
{
    const float* x = (const float*)d_in[0];
    const float* W = (const float*)d_in[1];
    float* out = (float*)d_out;

    const int Ntok = in_sizes[0] / D_MODEL;          // 16384
    const int nblk = Ntok / TB;                      // 256

    const size_t wh_elems = (size_t)NE * D_MODEL;    // 131072 shorts each
    const size_t need = wh_elems * 2 * 2
                      + ((size_t)nblk * NE + nblk) * 4
                      + (size_t)nblk * NE * 4 + 1024;

    if ((Ntok % TB) == 0 && (nblk % 4) == 0 && ws_size >= need) {
        short* wsh     = (short*)d_ws;               // Wh [64][2048]
        short* wsl     = wsh + wh_elems;             // Wl
        float* ws_prob = (float*)(wsl + wh_elems);
        float* ws_z    = ws_prob + (size_t)nblk * NE;
        int*   ws_cnt  = (int*)(ws_z + nblk);

        wcvt_kernel<<<NE, 256, 0, stream>>>(W, wsh, wsl);
        router_fused_db<<<nblk, 512, 0, stream>>>(x, wsh, wsl, out,
                                                  ws_prob, ws_z, ws_cnt, Ntok);
        router_final2<<<1, 256, 0, stream>>>(ws_prob, ws_z, ws_cnt, out, Ntok, nblk);
    } else {
        const int nb = Ntok / 64;
        float* ws_prob = (float*)d_ws;
        float* ws_z    = ws_prob + (size_t)nb * NE;
        int*   ws_cnt  = (int*)(ws_z + nb);
        router_main_fb<<<nb, 256, 0, stream>>>(x, W, out, ws_prob, ws_z, ws_cnt, Ntok);
        router_final2<<<1, 256, 0, stream>>>(ws_prob, ws_z, ws_cnt, out, Ntok, nb);
    }
}